// Round 5
// baseline (413.769 us; speedup 1.0000x reference)
//
#include <hip/hip_runtime.h>

// Causal Toeplitz-conv GEMM. y[b,h,n] = sum_{m<=n} u[b,h,m]*K[h,n-m] + D[h]*u[b,h,n]
// Out complex64 interleaved (re,0). Block=(h, 16 tiles of 128), 4 waves (2x2),
// wave 64x64 via 4x4 x v_mfma_f32_16x16x32_bf16.
// A-operand (Toeplitz K) from global KR8 (8 shift copies, L1/L2-resident),
// FULL register double-buffer (10 frags) -> no same-iter load->MFMA dependency.
// u staged f32->bf16 inline (no cvt_u pre-pass). LDS = sliding 17-slot u-window.

#define TILE 128
#define IGRP 16
#define SLOTS 17
#define BROW 136                        // shorts per (slot,b) row (128+8)
#define SLOT_STRIDE (8 * BROW)          // 1088 shorts
#define BS_SHORTS (SLOTS * SLOT_STRIDE) // 18496
#define KRC_STRIDE 264                  // tier0 LDS K row (shorts)
#define KRC_BUF (8 * KRC_STRIDE)        // 2112 shorts per buffer
#define EP_STRIDE 132

typedef short bf16x8 __attribute__((ext_vector_type(8)));
typedef float f32x4 __attribute__((ext_vector_type(4)));

__device__ __forceinline__ unsigned short f2bf(float f) {
    unsigned int u = __float_as_uint(f);
    u = (u + 0x7fffu + ((u >> 16) & 1u)) >> 16;  // RNE
    return (unsigned short)u;
}

// KR8[h][r][x] = bf16(K[h][L-1-(x-r)]) for x-r in [0,L), else 0.  r in 0..7.
__global__ void build_KR8(const float* __restrict__ K, unsigned short* __restrict__ KR8,
                          int L, int RS) {
    int x = blockIdx.x * 256 + threadIdx.x;
    int r = blockIdx.y;
    long h = blockIdx.z;
    if (x >= RS) return;
    int t = x - r;
    unsigned short v = 0;
    if (t >= 0 && t < L) v = f2bf(K[h * L + (L - 1 - t)]);
    KR8[(h * 8 + r) * (long)RS + x] = v;
}

template <int UK>
__global__ __launch_bounds__(256, 3) void conv_main(
    const float* __restrict__ u, const float* __restrict__ Kc,
    const float* __restrict__ Dp, const unsigned short* __restrict__ KR8,
    float* __restrict__ outf, int H, int L, int G, int RS, int cplx, long out_floats)
{
    __shared__ __align__(16) char smem[UK ? (BS_SHORTS * 2) : (BS_SHORTS * 2 + 2 * KRC_BUF * 2)];
    unsigned short* Bs = (unsigned short*)smem;
    unsigned short* Krc = (unsigned short*)(smem + BS_SHORTS * 2);  // tier0 only
    float* Ep = (float*)smem;

    const int tid  = threadIdx.x;
    const int lane = tid & 63;
    const int wv   = tid >> 6;
    const int wm   = wv >> 1;
    const int wn   = wv & 1;
    const int m    = lane & 15;
    const int quad = lane >> 4;

    const int bx = blockIdx.x;
    const int h  = bx % H;
    const int g  = (G - 1) - (bx / H);  // big groups first
    const int i0 = g * IGRP;
    const int dmax = i0 + IGRP - 1;

    const int rA = (m + 1) & 7;
    const int t0b = 127 - wm * 64 - m + quad * 8;   // t0 base (rb=0,kc=0)
    const int cB = (m & 7) * BROW + quad * 8;       // shorts

    // A source pointer (UK=1): byte addr into KR8, slides -256 B per iter
    const char* pA = (const char*)(KR8 + ((long)(h * 8 + rA)) * RS)
                   + 2 * ((long)(L - TILE) + t0b + rA);
    // A source (UK=0): LDS Krc byte offset
    const int cAb = 2 * (rA * KRC_STRIDE + t0b + rA);

    // tier0 K-staging constants
    int ldsK[5], taK[5];
    bool vK[5];
    if (UK == 0) {
        #pragma unroll
        for (int p = 0; p < 5; ++p) {
            int wi = tid + p * 256;
            vK[p] = wi < 1056;
            int rp = vK[p] ? (wi / 132) : 0;
            int tp = (wi - rp * 132) * 2;
            ldsK[p] = rp * KRC_STRIDE + tp;
            taK[p] = vK[p] ? (tp - rp) : -1000;
        }
    }
    const float* Kfrow = Kc + (long)h * L;

    // B staging: one (b-row, 4-float) chunk per thread, f32 -> bf16 inline
    const int bb = tid >> 5;
    const int q8 = (tid & 31) * 4;
    const long ubase = ((long)bb * H + h) * L;

    f32x4 acc[4][4];
    {
        f32x4 z = {0.f, 0.f, 0.f, 0.f};
        #pragma unroll
        for (int a = 0; a < 4; ++a)
            #pragma unroll
            for (int b = 0; b < 4; ++b) acc[a][b] = z;
    }

    int jc[4], sc4[4];
    #pragma unroll
    for (int nb = 0; nb < 4; ++nb) {
        int il = wn * 8 + nb * 2 + (m >> 3);
        jc[nb] = i0 + il;
        sc4[nb] = jc[nb] % SLOTS;
    }
    int slotw = (i0 >= 1) ? ((i0 - 1) % SLOTS) : (SLOTS - 1);

    // ---- prologue: stage 16 window tiles; load ALL af for d=0 ----
    #pragma unroll
    for (int batch = 0; batch < 2; ++batch) {
        uint2 a8[8];
        #pragma unroll
        for (int q = 0; q < 8; ++q) {
            int j = i0 + batch * 8 + q;
            float4 v = *(const float4*)(u + ubase + (long)j * TILE + q8);
            a8[q].x = f2bf(v.x) | ((unsigned)f2bf(v.y) << 16);
            a8[q].y = f2bf(v.z) | ((unsigned)f2bf(v.w) << 16);
        }
        #pragma unroll
        for (int q = 0; q < 8; ++q) {
            int j = i0 + batch * 8 + q;
            *(uint2*)(Bs + (j % SLOTS) * SLOT_STRIDE + bb * BROW + q8) = a8[q];
        }
    }
    if (UK == 0) {
        #pragma unroll
        for (int p = 0; p < 5; ++p) {
            if (vK[p]) {
                unsigned int s0 = 0, s1 = 0;
                int ta = taK[p];
                int ka = 127 - ta;
                if (ta >= 0 && ta < 256 && ka >= 0) s0 = f2bf(Kfrow[ka]);
                if (ta + 1 >= 0 && ta + 1 < 256 && (ka - 1) >= 0) s1 = f2bf(Kfrow[ka - 1]);
                *(unsigned int*)(Krc + ldsK[p]) = s0 | (s1 << 16);
            }
        }
    }
    bf16x8 af[10], afn[10];
    if (UK) {
        #pragma unroll
        for (int o = 0; o < 10; ++o) af[o] = *(const bf16x8*)(pA + (o - 3) * 32);
    }
    __syncthreads();

    const bf16x8 z8 = {};

    // ---- main loop: one barrier per iter; zero same-iter load->MFMA deps ----
    for (int d = 0; d <= dmax; ++d) {
        const int dn = d + 1;
        const int jn = i0 - dn;

        // A prefetch for next iter (longest latency -> issue first)
        if (UK) {
            if (d < dmax) {
                #pragma unroll
                for (int o = 0; o < 10; ++o) afn[o] = *(const bf16x8*)(pA - 256 + (o - 3) * 32);
            }
        } else {
            const char* Ab = (const char*)Krc + (d & 1) * (KRC_BUF * 2) + cAb;
            #pragma unroll
            for (int o = 0; o < 10; ++o) af[o] = *(const bf16x8*)(Ab + (o - 3) * 32);
        }

        // stage next B tile (f32 load + inline cvt)
        uint2 bv = {0u, 0u};
        if (jn >= 0) {
            float4 v = *(const float4*)(u + ubase + (long)jn * TILE + q8);
            bv.x = f2bf(v.x) | ((unsigned)f2bf(v.y) << 16);
            bv.y = f2bf(v.z) | ((unsigned)f2bf(v.w) << 16);
        }

        // tier0: K window for next iter
        unsigned int kv[5] = {0u, 0u, 0u, 0u, 0u};
        if (UK == 0 && dn <= dmax) {
            #pragma unroll
            for (int p = 0; p < 5; ++p) {
                unsigned int s0 = 0, s1 = 0;
                int ta = taK[p];
                if (vK[p]) {
                    int ka = dn * TILE + 127 - ta;
                    if (ta >= 0 && ta < 256 && ka >= 0) s0 = f2bf(Kfrow[ka]);
                    if (ta + 1 >= 0 && ta + 1 < 256 && (ka - 1) >= 0) s1 = f2bf(Kfrow[ka - 1]);
                }
                kv[p] = s0 | (s1 << 16);
            }
        }

        // ---- compute (af in regs, B from LDS) ----
        const int dlim = d - i0;
        const unsigned short* Bp[4];
        #pragma unroll
        for (int nb = 0; nb < 4; ++nb)
            Bp[nb] = Bs + sc4[nb] * SLOT_STRIDE + cB;

        #pragma unroll
        for (int kc = 0; kc < 4; ++kc) {
            #pragma unroll
            for (int nb = 0; nb < 4; ++nb) {
                const int nbg = wn * 4 + nb;
                if (2 * nbg + 1 >= dlim) {
                    bf16x8 bfr = *(const bf16x8*)(Bp[nb] + kc * 32);
                    if (2 * nbg + 1 == dlim) bfr = (jc[nb] < 0) ? z8 : bfr;  // boundary col mask
                    acc[0][nb] = __builtin_amdgcn_mfma_f32_16x16x32_bf16(af[3 + 2 * kc], bfr, acc[0][nb], 0, 0, 0);
                    acc[1][nb] = __builtin_amdgcn_mfma_f32_16x16x32_bf16(af[2 + 2 * kc], bfr, acc[1][nb], 0, 0, 0);
                    acc[2][nb] = __builtin_amdgcn_mfma_f32_16x16x32_bf16(af[1 + 2 * kc], bfr, acc[2][nb], 0, 0, 0);
                    acc[3][nb] = __builtin_amdgcn_mfma_f32_16x16x32_bf16(af[0 + 2 * kc], bfr, acc[3][nb], 0, 0, 0);
                }
            }
        }

        // commit staged data for next iter
        if (UK == 0 && dn <= dmax) {
            unsigned short* Kw = Krc + (dn & 1) * KRC_BUF;
            #pragma unroll
            for (int p = 0; p < 5; ++p)
                if (vK[p]) *(unsigned int*)(Kw + ldsK[p]) = kv[p];
        }
        if (jn >= 0)
            *(uint2*)(Bs + slotw * SLOT_STRIDE + bb * BROW + q8) = bv;

        slotw = slotw ? slotw - 1 : SLOTS - 1;
        #pragma unroll
        for (int nb = 0; nb < 4; ++nb) {
            jc[nb]--;
            sc4[nb] = sc4[nb] ? sc4[nb] - 1 : SLOTS - 1;
        }
        if (UK) {
            #pragma unroll
            for (int o = 0; o < 10; ++o) af[o] = afn[o];
            pA -= 256;
        }
        __syncthreads();
    }

    // ---- epilogue: LDS transpose (2 passes), skip-add, store ----
    const float Dh = Dp[h];
    const int ec = tid >> 2;
    const int ps = (tid & 3) * 32;
    #pragma unroll
    for (int pass = 0; pass < 2; ++pass) {
        if (wn == pass) {
            #pragma unroll
            for (int rb = 0; rb < 4; ++rb) {
                int p = wm * 64 + rb * 16 + quad * 4;  // C/D row = quad*4+reg
                #pragma unroll
                for (int nb = 0; nb < 4; ++nb) {
                    int cloc = nb * 16 + m;            // C/D col = lane&15
                    *(f32x4*)(Ep + cloc * EP_STRIDE + p) = acc[rb][nb];
                }
            }
        }
        __syncthreads();
        {
            int cg = pass * 64 + ec;
            int b  = cg & 7;
            int i  = i0 + (cg >> 3);
            long base = ((long)b * H + h) * L + (long)i * TILE + ps;
            const float* ep = Ep + ec * EP_STRIDE + ps;
            const float* us = u + base;
            if (cplx) {
                if (2 * (base + 32) <= out_floats) {
                    float4* o = (float4*)(outf + 2 * base);
                    #pragma unroll
                    for (int k4 = 0; k4 < 8; ++k4) {
                        float4 uv = ((const float4*)us)[k4];
                        float4 ev = *(const float4*)(ep + k4 * 4);
                        float4 o1, o2;
                        o1.x = ev.x + Dh * uv.x; o1.y = 0.f;
                        o1.z = ev.y + Dh * uv.y; o1.w = 0.f;
                        o2.x = ev.z + Dh * uv.z; o2.y = 0.f;
                        o2.z = ev.w + Dh * uv.w; o2.w = 0.f;
                        o[k4 * 2]     = o1;
                        o[k4 * 2 + 1] = o2;
                    }
                }
            } else {
                if (base + 32 <= out_floats) {
                    float4* o = (float4*)(outf + base);
                    #pragma unroll
                    for (int k4 = 0; k4 < 8; ++k4) {
                        float4 uv = ((const float4*)us)[k4];
                        float4 ev = *(const float4*)(ep + k4 * 4);
                        float4 ov;
                        ov.x = ev.x + Dh * uv.x;
                        ov.y = ev.y + Dh * uv.y;
                        ov.z = ev.z + Dh * uv.z;
                        ov.w = ev.w + Dh * uv.w;
                        o[k4] = ov;
                    }
                }
            }
        }
        __syncthreads();
    }
}

extern "C" void kernel_launch(void* const* d_in, const int* in_sizes, int n_in,
                              void* d_out, int out_size, void* d_ws, size_t ws_size,
                              hipStream_t stream) {
    const float* u  = (const float*)d_in[0];
    const float* Kc = (const float*)d_in[1];
    const float* Dp = (const float*)d_in[2];
    const int H = in_sizes[2];
    const int L = in_sizes[1] / H;          // 8192
    const int G = L / (TILE * IGRP);        // 4
    const int RS = L + 272;
    const int cplx = (out_size >= 2 * in_sizes[0]) ? 1 : 0;

    const size_t kr8_bytes = (size_t)H * 8 * RS * 2;
    const int tier = (ws_size >= kr8_bytes) ? 1 : 0;
    unsigned short* KR8 = (unsigned short*)d_ws;

    if (tier) {
        dim3 gk((RS + 255) / 256, 8, H);
        build_KR8<<<gk, 256, 0, stream>>>(Kc, KR8, L, RS);
        conv_main<1><<<H * G, 256, 0, stream>>>(u, Kc, Dp, KR8, (float*)d_out,
                                                H, L, G, RS, cplx, (long)out_size);
    } else {
        conv_main<0><<<H * G, 256, 0, stream>>>(u, Kc, Dp, KR8, (float*)d_out,
                                                H, L, G, RS, cplx, (long)out_size);
    }
}

// Round 6
// 337.276 us; speedup vs baseline: 1.2268x; 1.2268x over previous
//
#include <hip/hip_runtime.h>

// Causal Toeplitz-conv GEMM. y[b,h,n] = sum_{m<=n} u[b,h,m]*K[h,n-m] + D[h]*u[b,h,n]
// Out complex64 interleaved (re,0). Block=(h, 16 tiles of 128), 4 waves (2x2),
// wave 64x64 via 4x4 x v_mfma_f32_16x16x32_bf16.
// Tier1: A from global KR8 (8 shift copies); TWO d-steps per barrier (super-iter),
// 19-slot sliding LDS u-window (bf16 via cvt_u pre-pass); A-frag reuse across steps.
// Tier0 (small ws): R4-style single-step loop, K staged in LDS, f32 u inline.

#define TILE 128
#define IGRP 16
#define S1 19                  // tier1 window slots
#define S0 17                  // tier0 window slots
#define SLOT_SH 1024           // shorts per slot: 8 rows x 128
#define KRC_STRIDE 264
#define KRC_BUF (8 * KRC_STRIDE)
#define EP_STRIDE 132

typedef short bf16x8 __attribute__((ext_vector_type(8)));
typedef float f32x4 __attribute__((ext_vector_type(4)));
#define MFMA16(a, b, c) __builtin_amdgcn_mfma_f32_16x16x32_bf16(a, b, c, 0, 0, 0)

__device__ __forceinline__ unsigned short f2bf(float f) {
    unsigned int u = __float_as_uint(f);
    u = (u + 0x7fffu + ((u >> 16) & 1u)) >> 16;  // RNE
    return (unsigned short)u;
}

__global__ void cvt_u_bf16(const float* __restrict__ u, unsigned short* __restrict__ ubf, int n4) {
    int idx = blockIdx.x * 256 + threadIdx.x;
    if (idx >= n4) return;
    float4 v = ((const float4*)u)[idx];
    ushort4 o;
    o.x = f2bf(v.x); o.y = f2bf(v.y); o.z = f2bf(v.z); o.w = f2bf(v.w);
    ((ushort4*)ubf)[idx] = o;
}

// KR8[h][r][x] = bf16(K[h][L-1-(x-r)]) for x-r in [0,L), else 0.  r in 0..7.
__global__ void build_KR8(const float* __restrict__ K, unsigned short* __restrict__ KR8,
                          int L, int RS) {
    int x = blockIdx.x * 256 + threadIdx.x;
    int r = blockIdx.y;
    long h = blockIdx.z;
    if (x >= RS) return;
    int t = x - r;
    unsigned short v = 0;
    if (t >= 0 && t < L) v = f2bf(K[h * L + (L - 1 - t)]);
    KR8[(h * 8 + r) * (long)RS + x] = v;
}

// ---------------- epilogue (shared) ----------------
#define EPILOGUE()                                                                 \
    {                                                                              \
        const float Dh = Dp[h];                                                    \
        const int ec = tid >> 2;                                                   \
        const int ps = (tid & 3) * 32;                                             \
        _Pragma("unroll")                                                          \
        for (int pass = 0; pass < 2; ++pass) {                                     \
            if (wn == pass) {                                                      \
                _Pragma("unroll")                                                  \
                for (int rb = 0; rb < 4; ++rb) {                                   \
                    int p = wm * 64 + rb * 16 + quad * 4;                          \
                    _Pragma("unroll")                                              \
                    for (int nb = 0; nb < 4; ++nb) {                               \
                        int cloc = nb * 16 + m;                                    \
                        *(f32x4*)(Ep + cloc * EP_STRIDE + p) = acc[rb][nb];        \
                    }                                                              \
                }                                                                  \
            }                                                                      \
            __syncthreads();                                                       \
            {                                                                      \
                int cg = pass * 64 + ec;                                           \
                int b = cg & 7;                                                    \
                int i = i0 + (cg >> 3);                                            \
                long base = ((long)b * H + h) * L + (long)i * TILE + ps;           \
                const float* ep = Ep + ec * EP_STRIDE + ps;                        \
                const float* us = u + base;                                        \
                if (cplx) {                                                        \
                    if (2 * (base + 32) <= out_floats) {                           \
                        float4* o = (float4*)(outf + 2 * base);                    \
                        _Pragma("unroll")                                          \
                        for (int k4 = 0; k4 < 8; ++k4) {                           \
                            float4 uv = ((const float4*)us)[k4];                   \
                            float4 ev = *(const float4*)(ep + k4 * 4);             \
                            float4 o1, o2;                                         \
                            o1.x = ev.x + Dh * uv.x; o1.y = 0.f;                   \
                            o1.z = ev.y + Dh * uv.y; o1.w = 0.f;                   \
                            o2.x = ev.z + Dh * uv.z; o2.y = 0.f;                   \
                            o2.z = ev.w + Dh * uv.w; o2.w = 0.f;                   \
                            o[k4 * 2] = o1;                                        \
                            o[k4 * 2 + 1] = o2;                                    \
                        }                                                          \
                    }                                                              \
                } else {                                                           \
                    if (base + 32 <= out_floats) {                                 \
                        float4* o = (float4*)(outf + base);                        \
                        _Pragma("unroll")                                          \
                        for (int k4 = 0; k4 < 8; ++k4) {                           \
                            float4 uv = ((const float4*)us)[k4];                   \
                            float4 ev = *(const float4*)(ep + k4 * 4);             \
                            float4 ov;                                             \
                            ov.x = ev.x + Dh * uv.x;                               \
                            ov.y = ev.y + Dh * uv.y;                               \
                            ov.z = ev.z + Dh * uv.z;                               \
                            ov.w = ev.w + Dh * uv.w;                               \
                            o[k4] = ov;                                            \
                        }                                                          \
                    }                                                              \
                }                                                                  \
            }                                                                      \
            __syncthreads();                                                       \
        }                                                                          \
    }

#define COMPUTE_STEP(AF, DL, TH, SL0, SL1, SL2, SL3)                               \
    {                                                                              \
        const int dl_ = (DL);                                                      \
        const unsigned short* bp_[4] = {                                           \
            Bs + (SL0) * SLOT_SH + cB, Bs + (SL1) * SLOT_SH + cB,                  \
            Bs + (SL2) * SLOT_SH + cB, Bs + (SL3) * SLOT_SH + cB};                 \
        _Pragma("unroll")                                                          \
        for (int kc = 0; kc < 4; ++kc) {                                           \
            _Pragma("unroll")                                                      \
            for (int nb = 0; nb < 4; ++nb) {                                       \
                const int nbg = wn * 4 + nb;                                       \
                if (2 * nbg + 1 >= dl_) {                                          \
                    bf16x8 bfr = *(const bf16x8*)(bp_[nb] + kc * 32);              \
                    if (2 * nbg + 1 == dl_) bfr = (jc[nb] < (TH)) ? z8 : bfr;      \
                    acc[0][nb] = MFMA16(AF[3 + 2 * kc], bfr, acc[0][nb]);          \
                    acc[1][nb] = MFMA16(AF[2 + 2 * kc], bfr, acc[1][nb]);          \
                    acc[2][nb] = MFMA16(AF[1 + 2 * kc], bfr, acc[2][nb]);          \
                    acc[3][nb] = MFMA16(AF[0 + 2 * kc], bfr, acc[3][nb]);          \
                }                                                                  \
            }                                                                      \
        }                                                                          \
    }

__device__ __forceinline__ int dec19(int x) { return x == 0 ? S1 - 1 : x - 1; }
__device__ __forceinline__ int dec17(int x) { return x == 0 ? S0 - 1 : x - 1; }

// ---------------- tier1: super-iter (2 steps/barrier), A from KR8 ----------------
__global__ __launch_bounds__(256, 2) void conv_tier1(
    const float* __restrict__ u, const float* __restrict__ Dp,
    const unsigned short* __restrict__ ubf, const unsigned short* __restrict__ KR8,
    float* __restrict__ outf, int H, int L, int G, int RS, int cplx, long out_floats)
{
    __shared__ __align__(16) char smem[S1 * SLOT_SH * 2];  // 38912 B
    unsigned short* Bs = (unsigned short*)smem;
    float* Ep = (float*)smem;

    const int tid  = threadIdx.x;
    const int lane = tid & 63;
    const int wv   = tid >> 6;
    const int wm   = wv >> 1;
    const int wn   = wv & 1;
    const int m    = lane & 15;
    const int quad = lane >> 4;

    const int bx = blockIdx.x;
    const int h  = bx % H;
    const int g  = (G - 1) - (bx / H);  // big groups first
    const int i0 = g * IGRP;
    const int dmax = i0 + IGRP - 1;     // dmax+1 is even

    const int rA  = (m + 1) & 7;
    const int t0b = 127 - wm * 64 - m + quad * 8;
    const int cB  = (m & 7) * TILE + quad * 8;

    const char* pA = (const char*)(KR8 + ((long)(h * 8 + rA)) * RS)
                   + 2 * ((long)(L - TILE) + t0b + rA);

    // staging mapping: 2 tiles per super-iter, 128 threads each, 16 B/thread
    const int sel = tid >> 7;            // 0 -> tile jn0, 1 -> tile jn1
    const int bb2 = (tid & 127) >> 4;    // b row
    const int q16 = (tid & 15) * 8;      // short offset within row
    const long ubase2 = ((long)bb2 * H + h) * L;

    f32x4 acc[4][4];
    {
        f32x4 z = {0.f, 0.f, 0.f, 0.f};
        #pragma unroll
        for (int a = 0; a < 4; ++a)
            #pragma unroll
            for (int b = 0; b < 4; ++b) acc[a][b] = z;
    }

    int jc[4], sc[4];
    #pragma unroll
    for (int nb = 0; nb < 4; ++nb) {
        int il = wn * 8 + nb * 2 + (m >> 3);
        jc[nb] = i0 + il;
        sc[nb] = jc[nb] % S1;
    }
    int myslot = (((i0 - 2 - sel) % S1) + S1) % S1;  // slot for this thread's staged tile

    // ---- prologue: A0 frags + stage window tiles [i0-1 .. i0+15] ----
    bf16x8 A0[10], A1[10], An[8];
    #pragma unroll
    for (int o = 0; o < 10; ++o) A0[o] = *(const bf16x8*)(pA + (o - 3) * 32);
    for (int rr = 0; rr < 9; ++rr) {
        int tj = i0 - 1 + rr * 2 + sel;
        if (tj >= 0 && tj <= i0 + 15) {
            uint4 v = *(const uint4*)(ubf + ubase2 + (long)tj * TILE + q16);
            *(uint4*)(Bs + (tj % S1) * SLOT_SH + bb2 * TILE + q16) = v;
        }
    }
    __syncthreads();

    const bf16x8 z8 = {};

    // ---- main loop: 2 steps per barrier ----
    for (int d = 0; d <= dmax; d += 2) {
        // A frags for step d+1 (8 new + 2 reused)
        #pragma unroll
        for (int o = 0; o < 8; ++o) A1[o] = *(const bf16x8*)(pA - 256 + (o - 3) * 32);
        A1[8] = A0[0]; A1[9] = A0[1];

        // staging load for next super-iter (in flight across both halves)
        const int jn = i0 - d - 2 - sel;
        uint4 bv = {0u, 0u, 0u, 0u};
        if (jn >= 0) bv = *(const uint4*)(ubf + ubase2 + (long)jn * TILE + q16);

        // first half (step d)
        COMPUTE_STEP(A0, d - i0, 0, sc[0], sc[1], sc[2], sc[3]);

        // A prefetch for step d+2 (consumed next super-iter)
        if (d + 2 <= dmax) {
            #pragma unroll
            for (int o = 0; o < 8; ++o) An[o] = *(const bf16x8*)(pA - 512 + (o - 3) * 32);
        }

        // second half (step d+1)
        {
            int sb0 = dec19(sc[0]), sb1 = dec19(sc[1]), sb2 = dec19(sc[2]), sb3 = dec19(sc[3]);
            COMPUTE_STEP(A1, d + 1 - i0, 1, sb0, sb1, sb2, sb3);
            sc[0] = dec19(sb0); sc[1] = dec19(sb1); sc[2] = dec19(sb2); sc[3] = dec19(sb3);
        }

        // commit staged tile
        if (jn >= 0)
            *(uint4*)(Bs + myslot * SLOT_SH + bb2 * TILE + q16) = bv;
        myslot = myslot >= 2 ? myslot - 2 : myslot + (S1 - 2);

        #pragma unroll
        for (int nb = 0; nb < 4; ++nb) jc[nb] -= 2;

        #pragma unroll
        for (int o = 0; o < 8; ++o) A0[o] = An[o];
        A0[8] = A1[0]; A0[9] = A1[1];
        pA -= 512;
        __syncthreads();
    }

    EPILOGUE();
}

// ---------------- tier0: single-step, K via LDS, u f32 inline (fallback) ----------------
__global__ __launch_bounds__(256, 2) void conv_tier0(
    const float* __restrict__ u, const float* __restrict__ Kc,
    const float* __restrict__ Dp, float* __restrict__ outf,
    int H, int L, int G, int cplx, long out_floats)
{
    __shared__ __align__(16) char smem[S0 * SLOT_SH * 2 + 2 * KRC_BUF * 2];  // 43264 B
    unsigned short* Bs = (unsigned short*)smem;
    unsigned short* Krc = (unsigned short*)(smem + S0 * SLOT_SH * 2);
    float* Ep = (float*)smem;

    const int tid  = threadIdx.x;
    const int lane = tid & 63;
    const int wv   = tid >> 6;
    const int wm   = wv >> 1;
    const int wn   = wv & 1;
    const int m    = lane & 15;
    const int quad = lane >> 4;

    const int bx = blockIdx.x;
    const int h  = bx % H;
    const int g  = (G - 1) - (bx / H);
    const int i0 = g * IGRP;
    const int dmax = i0 + IGRP - 1;

    const int rA  = (m + 1) & 7;
    const int t0b = 127 - wm * 64 - m + quad * 8;
    const int cB  = (m & 7) * TILE + quad * 8;
    const int cAb = 2 * (rA * KRC_STRIDE + t0b + rA);

    int ldsK[5], taK[5];
    bool vK[5];
    #pragma unroll
    for (int p = 0; p < 5; ++p) {
        int wi = tid + p * 256;
        vK[p] = wi < 1056;
        int rp = vK[p] ? (wi / 132) : 0;
        int tp = (wi - rp * 132) * 2;
        ldsK[p] = rp * KRC_STRIDE + tp;
        taK[p] = vK[p] ? (tp - rp) : -1000;
    }
    const float* Kfrow = Kc + (long)h * L;

    const int bb = tid >> 5;
    const int q8 = (tid & 31) * 4;
    const long ubase = ((long)bb * H + h) * L;

    f32x4 acc[4][4];
    {
        f32x4 z = {0.f, 0.f, 0.f, 0.f};
        #pragma unroll
        for (int a = 0; a < 4; ++a)
            #pragma unroll
            for (int b = 0; b < 4; ++b) acc[a][b] = z;
    }

    int jc[4], sc[4];
    #pragma unroll
    for (int nb = 0; nb < 4; ++nb) {
        int il = wn * 8 + nb * 2 + (m >> 3);
        jc[nb] = i0 + il;
        sc[nb] = jc[nb] % S0;
    }
    int slotw = (((i0 - 1) % S0) + S0) % S0;

    // prologue: stage 16 tiles + Krc[0]
    #pragma unroll
    for (int batch = 0; batch < 2; ++batch) {
        uint2 a8[8];
        #pragma unroll
        for (int q = 0; q < 8; ++q) {
            int j = i0 + batch * 8 + q;
            float4 v = *(const float4*)(u + ubase + (long)j * TILE + q8);
            a8[q].x = f2bf(v.x) | ((unsigned)f2bf(v.y) << 16);
            a8[q].y = f2bf(v.z) | ((unsigned)f2bf(v.w) << 16);
        }
        #pragma unroll
        for (int q = 0; q < 8; ++q) {
            int j = i0 + batch * 8 + q;
            *(uint2*)(Bs + (j % S0) * SLOT_SH + bb * TILE + q8) = a8[q];
        }
    }
    #pragma unroll
    for (int p = 0; p < 5; ++p) {
        if (vK[p]) {
            unsigned int s0 = 0, s1 = 0;
            int ta = taK[p];
            int ka = 127 - ta;
            if (ta >= 0 && ta < 256 && ka >= 0) s0 = f2bf(Kfrow[ka]);
            if (ta + 1 >= 0 && ta + 1 < 256 && (ka - 1) >= 0) s1 = f2bf(Kfrow[ka - 1]);
            *(unsigned int*)(Krc + ldsK[p]) = s0 | (s1 << 16);
        }
    }
    __syncthreads();

    const bf16x8 z8 = {};
    bf16x8 af[10];

    for (int d = 0; d <= dmax; ++d) {
        const int dn = d + 1;
        const int jn = i0 - dn;

        const char* Ab = (const char*)Krc + (d & 1) * (KRC_BUF * 2) + cAb;
        #pragma unroll
        for (int o = 0; o < 10; ++o) af[o] = *(const bf16x8*)(Ab + (o - 3) * 32);

        uint2 bv = {0u, 0u};
        if (jn >= 0) {
            float4 v = *(const float4*)(u + ubase + (long)jn * TILE + q8);
            bv.x = f2bf(v.x) | ((unsigned)f2bf(v.y) << 16);
            bv.y = f2bf(v.z) | ((unsigned)f2bf(v.w) << 16);
        }

        unsigned int kv[5] = {0u, 0u, 0u, 0u, 0u};
        if (dn <= dmax) {
            #pragma unroll
            for (int p = 0; p < 5; ++p) {
                unsigned int s0 = 0, s1 = 0;
                int ta = taK[p];
                if (vK[p]) {
                    int ka = dn * TILE + 127 - ta;
                    if (ta >= 0 && ta < 256 && ka >= 0) s0 = f2bf(Kfrow[ka]);
                    if (ta + 1 >= 0 && ta + 1 < 256 && (ka - 1) >= 0) s1 = f2bf(Kfrow[ka - 1]);
                }
                kv[p] = s0 | (s1 << 16);
            }
        }

        COMPUTE_STEP(af, d - i0, 0, sc[0], sc[1], sc[2], sc[3]);

        if (dn <= dmax) {
            unsigned short* Kw = Krc + (dn & 1) * KRC_BUF;
            #pragma unroll
            for (int p = 0; p < 5; ++p)
                if (vK[p]) *(unsigned int*)(Kw + ldsK[p]) = kv[p];
        }
        if (jn >= 0)
            *(uint2*)(Bs + slotw * SLOT_SH + bb * TILE + q8) = bv;

        slotw = dec17(slotw);
        #pragma unroll
        for (int nb = 0; nb < 4; ++nb) {
            jc[nb]--;
            sc[nb] = dec17(sc[nb]);
        }
        __syncthreads();
    }

    EPILOGUE();
}

extern "C" void kernel_launch(void* const* d_in, const int* in_sizes, int n_in,
                              void* d_out, int out_size, void* d_ws, size_t ws_size,
                              hipStream_t stream) {
    const float* u  = (const float*)d_in[0];
    const float* Kc = (const float*)d_in[1];
    const float* Dp = (const float*)d_in[2];
    const int H = in_sizes[2];
    const int L = in_sizes[1] / H;          // 8192
    const int G = L / (TILE * IGRP);        // 4
    const int RS = L + 272;
    const int cplx = (out_size >= 2 * in_sizes[0]) ? 1 : 0;

    const size_t kr8_bytes = (size_t)H * 8 * RS * 2;
    const size_t u_bytes   = (size_t)in_sizes[0] * 2;
    unsigned short* KR8 = (unsigned short*)d_ws;
    unsigned short* ubf = (unsigned short*)((char*)d_ws + kr8_bytes);

    if (ws_size >= kr8_bytes + u_bytes) {
        dim3 gk((RS + 255) / 256, 8, H);
        build_KR8<<<gk, 256, 0, stream>>>(Kc, KR8, L, RS);
        int n4 = in_sizes[0] / 4;
        cvt_u_bf16<<<(n4 + 255) / 256, 256, 0, stream>>>(u, ubf, n4);
        conv_tier1<<<H * G, 256, 0, stream>>>(u, Dp, ubf, KR8, (float*)d_out,
                                              H, L, G, RS, cplx, (long)out_size);
    } else {
        conv_tier0<<<H * G, 256, 0, stream>>>(u, Kc, Dp, (float*)d_out,
                                              H, L, G, cplx, (long)out_size);
    }
}

// Round 7
// 305.000 us; speedup vs baseline: 1.3566x; 1.1058x over previous
//
#include <hip/hip_runtime.h>

// Causal Toeplitz-conv GEMM. y[b,h,n] = sum_{m<=n} u[b,h,m]*K[h,n-m] + D[h]*u[b,h,n]
// Out complex64 interleaved (re,0). Block=(h, 16 tiles of 128), 4 waves (2x2),
// wave 64x64 via 4x4 x v_mfma_f32_16x16x32_bf16.
// A-operand (Toeplitz K) from global KR8 (8 shift copies, L1/L2-resident),
// half-register double-buffer (15 frags: fits 170-reg cap at (256,3)).
// u staged f32 -> bf16 with the PACK DEFERRED to the post-compute commit point
// (no cvt_u pre-pass, no exposed load latency). LDS = sliding 17-slot u-window,
// row stride 136 shorts (conflict-minimal, measured 8.9e6 vs 6.1e7 at 128).

#define TILE 128
#define IGRP 16
#define SLOTS 17
#define BROW 136                        // shorts per (slot,b) row (128+8)
#define SLOT_STRIDE (8 * BROW)          // 1088 shorts
#define BS_SHORTS (SLOTS * SLOT_STRIDE) // 18496
#define KRC_STRIDE 264                  // tier0 LDS K row (shorts)
#define KRC_BUF (8 * KRC_STRIDE)        // 2112 shorts per buffer
#define EP_STRIDE 132

typedef short bf16x8 __attribute__((ext_vector_type(8)));
typedef float f32x4 __attribute__((ext_vector_type(4)));

__device__ __forceinline__ unsigned short f2bf(float f) {
    unsigned int u = __float_as_uint(f);
    u = (u + 0x7fffu + ((u >> 16) & 1u)) >> 16;  // RNE
    return (unsigned short)u;
}

// KR8[h][r][x] = bf16(K[h][L-1-(x-r)]) for x-r in [0,L), else 0.  r in 0..7.
__global__ void build_KR8(const float* __restrict__ K, unsigned short* __restrict__ KR8,
                          int L, int RS) {
    int x = blockIdx.x * 256 + threadIdx.x;
    int r = blockIdx.y;
    long h = blockIdx.z;
    if (x >= RS) return;
    int t = x - r;
    unsigned short v = 0;
    if (t >= 0 && t < L) v = f2bf(K[h * L + (L - 1 - t)]);
    KR8[(h * 8 + r) * (long)RS + x] = v;
}

template <int UK>
__global__ __launch_bounds__(256, 3) void conv_main(
    const float* __restrict__ u, const float* __restrict__ Kc,
    const float* __restrict__ Dp, const unsigned short* __restrict__ KR8,
    float* __restrict__ outf, int H, int L, int G, int RS, int cplx, long out_floats)
{
    __shared__ __align__(16) char smem[UK ? (BS_SHORTS * 2) : (BS_SHORTS * 2 + 2 * KRC_BUF * 2)];
    unsigned short* Bs = (unsigned short*)smem;
    unsigned short* Krc = (unsigned short*)(smem + BS_SHORTS * 2);  // tier0 only
    float* Ep = (float*)smem;

    const int tid  = threadIdx.x;
    const int lane = tid & 63;
    const int wv   = tid >> 6;
    const int wm   = wv >> 1;
    const int wn   = wv & 1;
    const int m    = lane & 15;
    const int quad = lane >> 4;

    const int bx = blockIdx.x;
    const int h  = bx % H;
    const int g  = (G - 1) - (bx / H);  // big groups first
    const int i0 = g * IGRP;
    const int dmax = i0 + IGRP - 1;

    const int rA = (m + 1) & 7;
    const int t0b = 127 - wm * 64 - m + quad * 8;   // t0 base (rb=0,kc=0)
    const int cB = (m & 7) * BROW + quad * 8;       // shorts

    // A source pointer (UK=1): byte addr into KR8, slides -256 B per iter
    const char* pA = (const char*)(KR8 + ((long)(h * 8 + rA)) * RS)
                   + 2 * ((long)(L - TILE) + t0b + rA);
    // A source (UK=0): LDS Krc byte offset
    const int cAb = 2 * (rA * KRC_STRIDE + t0b + rA);

    // tier0 K-staging constants (5 chunks cover 1056 u32)
    int ldsK[5], taK[5];
    bool vK[5];
    if (UK == 0) {
        #pragma unroll
        for (int p = 0; p < 5; ++p) {
            int wi = tid + p * 256;
            vK[p] = wi < 1056;
            int rp = vK[p] ? (wi / 132) : 0;
            int tp = (wi - rp * 132) * 2;
            ldsK[p] = rp * KRC_STRIDE + tp;
            taK[p] = vK[p] ? (tp - rp) : -1000;
        }
    }
    const float* Kfrow = Kc + (long)h * L;

    // B staging: one (b-row, 4-float) chunk per thread
    const int bb = tid >> 5;
    const int q8 = (tid & 31) * 4;
    const long ubase = ((long)bb * H + h) * L;

    f32x4 acc[4][4];
    {
        f32x4 z = {0.f, 0.f, 0.f, 0.f};
        #pragma unroll
        for (int a = 0; a < 4; ++a)
            #pragma unroll
            for (int b = 0; b < 4; ++b) acc[a][b] = z;
    }

    int jc[4], sc4[4];
    #pragma unroll
    for (int nb = 0; nb < 4; ++nb) {
        int il = wn * 8 + nb * 2 + (m >> 3);
        jc[nb] = i0 + il;
        sc4[nb] = jc[nb] % SLOTS;
    }
    int slotw = (i0 >= 1) ? ((i0 - 1) % SLOTS) : (SLOTS - 1);

    // ---- prologue: stage 16 window tiles (f32 -> bf16); tier0 also Krc[0] ----
    #pragma unroll
    for (int batch = 0; batch < 2; ++batch) {
        uint2 a8[8];
        #pragma unroll
        for (int q = 0; q < 8; ++q) {
            int j = i0 + batch * 8 + q;
            float4 v = *(const float4*)(u + ubase + (long)j * TILE + q8);
            a8[q].x = f2bf(v.x) | ((unsigned)f2bf(v.y) << 16);
            a8[q].y = f2bf(v.z) | ((unsigned)f2bf(v.w) << 16);
        }
        #pragma unroll
        for (int q = 0; q < 8; ++q) {
            int j = i0 + batch * 8 + q;
            *(uint2*)(Bs + (j % SLOTS) * SLOT_STRIDE + bb * BROW + q8) = a8[q];
        }
    }
    if (UK == 0) {
        #pragma unroll
        for (int p = 0; p < 5; ++p) {
            if (vK[p]) {
                unsigned int s0 = 0, s1 = 0;
                int ta = taK[p];
                int ka = 127 - ta;
                if (ta >= 0 && ta < 256 && ka >= 0) s0 = f2bf(Kfrow[ka]);
                if (ta + 1 >= 0 && ta + 1 < 256 && (ka - 1) >= 0) s1 = f2bf(Kfrow[ka - 1]);
                *(unsigned int*)(Krc + ldsK[p]) = s0 | (s1 << 16);
            }
        }
    }
    bf16x8 af[10], afn[5] = {};
    if (UK) {
        #pragma unroll
        for (int o = 0; o < 5; ++o) af[o] = *(const bf16x8*)(pA + (o - 3) * 32);
    }
    __syncthreads();

    const bf16x8 z8 = {};

    // ---- main loop: one barrier per iter ----
    for (int d = 0; d <= dmax; ++d) {
        const int dn = d + 1;
        const int jn = i0 - dn;

        // A frags: current-iter high half (UK1) or all from LDS (UK0)
        if (UK) {
            #pragma unroll
            for (int o = 5; o < 10; ++o) af[o] = *(const bf16x8*)(pA + (o - 3) * 32);
        } else {
            const char* Ab = (const char*)Krc + (d & 1) * (KRC_BUF * 2) + cAb;
            #pragma unroll
            for (int o = 0; o < 10; ++o) af[o] = *(const bf16x8*)(Ab + (o - 3) * 32);
        }

        // stage next B tile: ISSUE the f32 load now, pack AFTER compute
        float4 fv = {0.f, 0.f, 0.f, 0.f};
        if (jn >= 0)
            fv = *(const float4*)(u + ubase + (long)jn * TILE + q8);

        // A prefetch for next iter (no barrier dependency)
        if (UK) {
            if (d < dmax) {
                #pragma unroll
                for (int o = 0; o < 5; ++o) afn[o] = *(const bf16x8*)(pA - 256 + (o - 3) * 32);
            }
        }
        // tier0: K window values for next iter (guarded f32)
        unsigned int kv[5] = {0u, 0u, 0u, 0u, 0u};
        if (UK == 0 && dn <= dmax) {
            #pragma unroll
            for (int p = 0; p < 5; ++p) {
                unsigned int s0 = 0, s1 = 0;
                int ta = taK[p];
                if (vK[p]) {
                    int ka = dn * TILE + 127 - ta;
                    if (ta >= 0 && ta < 256 && ka >= 0) s0 = f2bf(Kfrow[ka]);
                    if (ta + 1 >= 0 && ta + 1 < 256 && (ka - 1) >= 0) s1 = f2bf(Kfrow[ka - 1]);
                }
                kv[p] = s0 | (s1 << 16);
            }
        }

        // ---- compute ----
        const int dlim = d - i0;
        const unsigned short* Bp[4];
        #pragma unroll
        for (int nb = 0; nb < 4; ++nb)
            Bp[nb] = Bs + sc4[nb] * SLOT_STRIDE + cB;

        #pragma unroll
        for (int kc = 0; kc < 4; ++kc) {
            #pragma unroll
            for (int nb = 0; nb < 4; ++nb) {
                const int nbg = wn * 4 + nb;
                if (2 * nbg + 1 >= dlim) {
                    bf16x8 bfr = *(const bf16x8*)(Bp[nb] + kc * 32);
                    if (2 * nbg + 1 == dlim) bfr = (jc[nb] < 0) ? z8 : bfr;  // boundary col mask
                    acc[0][nb] = __builtin_amdgcn_mfma_f32_16x16x32_bf16(af[3 + 2 * kc], bfr, acc[0][nb], 0, 0, 0);
                    acc[1][nb] = __builtin_amdgcn_mfma_f32_16x16x32_bf16(af[2 + 2 * kc], bfr, acc[1][nb], 0, 0, 0);
                    acc[2][nb] = __builtin_amdgcn_mfma_f32_16x16x32_bf16(af[1 + 2 * kc], bfr, acc[2][nb], 0, 0, 0);
                    acc[3][nb] = __builtin_amdgcn_mfma_f32_16x16x32_bf16(af[0 + 2 * kc], bfr, acc[3][nb], 0, 0, 0);
                }
            }
        }

        // commit staged data for next iter (pack happens HERE, behind the MFMAs)
        if (UK == 0 && dn <= dmax) {
            unsigned short* Kw = Krc + (dn & 1) * KRC_BUF;
            #pragma unroll
            for (int p = 0; p < 5; ++p)
                if (vK[p]) *(unsigned int*)(Kw + ldsK[p]) = kv[p];
        }
        if (jn >= 0) {
            uint2 bv;
            bv.x = f2bf(fv.x) | ((unsigned)f2bf(fv.y) << 16);
            bv.y = f2bf(fv.z) | ((unsigned)f2bf(fv.w) << 16);
            *(uint2*)(Bs + slotw * SLOT_STRIDE + bb * BROW + q8) = bv;
        }

        slotw = slotw ? slotw - 1 : SLOTS - 1;
        #pragma unroll
        for (int nb = 0; nb < 4; ++nb) {
            jc[nb]--;
            sc4[nb] = sc4[nb] ? sc4[nb] - 1 : SLOTS - 1;
        }
        if (UK) {
            #pragma unroll
            for (int o = 0; o < 5; ++o) af[o] = afn[o];
            pA -= 256;
        }
        __syncthreads();
    }

    // ---- epilogue: LDS transpose (2 passes), skip-add, store ----
    const float Dh = Dp[h];
    const int ec = tid >> 2;
    const int ps = (tid & 3) * 32;
    #pragma unroll
    for (int pass = 0; pass < 2; ++pass) {
        if (wn == pass) {
            #pragma unroll
            for (int rb = 0; rb < 4; ++rb) {
                int p = wm * 64 + rb * 16 + quad * 4;  // C/D row = quad*4+reg
                #pragma unroll
                for (int nb = 0; nb < 4; ++nb) {
                    int cloc = nb * 16 + m;            // C/D col = lane&15
                    *(f32x4*)(Ep + cloc * EP_STRIDE + p) = acc[rb][nb];
                }
            }
        }
        __syncthreads();
        {
            int cg = pass * 64 + ec;
            int b  = cg & 7;
            int i  = i0 + (cg >> 3);
            long base = ((long)b * H + h) * L + (long)i * TILE + ps;
            const float* ep = Ep + ec * EP_STRIDE + ps;
            const float* us = u + base;
            if (cplx) {
                if (2 * (base + 32) <= out_floats) {
                    float4* o = (float4*)(outf + 2 * base);
                    #pragma unroll
                    for (int k4 = 0; k4 < 8; ++k4) {
                        float4 uv = ((const float4*)us)[k4];
                        float4 ev = *(const float4*)(ep + k4 * 4);
                        float4 o1, o2;
                        o1.x = ev.x + Dh * uv.x; o1.y = 0.f;
                        o1.z = ev.y + Dh * uv.y; o1.w = 0.f;
                        o2.x = ev.z + Dh * uv.z; o2.y = 0.f;
                        o2.z = ev.w + Dh * uv.w; o2.w = 0.f;
                        o[k4 * 2]     = o1;
                        o[k4 * 2 + 1] = o2;
                    }
                }
            } else {
                if (base + 32 <= out_floats) {
                    float4* o = (float4*)(outf + base);
                    #pragma unroll
                    for (int k4 = 0; k4 < 8; ++k4) {
                        float4 uv = ((const float4*)us)[k4];
                        float4 ev = *(const float4*)(ep + k4 * 4);
                        float4 ov;
                        ov.x = ev.x + Dh * uv.x;
                        ov.y = ev.y + Dh * uv.y;
                        ov.z = ev.z + Dh * uv.z;
                        ov.w = ev.w + Dh * uv.w;
                        o[k4] = ov;
                    }
                }
            }
        }
        __syncthreads();
    }
}

extern "C" void kernel_launch(void* const* d_in, const int* in_sizes, int n_in,
                              void* d_out, int out_size, void* d_ws, size_t ws_size,
                              hipStream_t stream) {
    const float* u  = (const float*)d_in[0];
    const float* Kc = (const float*)d_in[1];
    const float* Dp = (const float*)d_in[2];
    const int H = in_sizes[2];
    const int L = in_sizes[1] / H;          // 8192
    const int G = L / (TILE * IGRP);        // 4
    const int RS = L + 272;
    const int cplx = (out_size >= 2 * in_sizes[0]) ? 1 : 0;

    const size_t kr8_bytes = (size_t)H * 8 * RS * 2;
    const int tier = (ws_size >= kr8_bytes) ? 1 : 0;
    unsigned short* KR8 = (unsigned short*)d_ws;

    if (tier) {
        dim3 gk((RS + 255) / 256, 8, H);
        build_KR8<<<gk, 256, 0, stream>>>(Kc, KR8, L, RS);
        conv_main<1><<<H * G, 256, 0, stream>>>(u, Kc, Dp, KR8, (float*)d_out,
                                                H, L, G, RS, cplx, (long)out_size);
    } else {
        conv_main<0><<<H * G, 256, 0, stream>>>(u, Kc, Dp, KR8, (float*)d_out,
                                                H, L, G, RS, cplx, (long)out_size);
    }
}